// Round 1
// baseline (715.512 us; speedup 1.0000x reference)
//
#include <hip/hip_runtime.h>

// Problem constants (from reference): F=50000, K=32, E=128, N=100000
#define F_TOTAL 50000
#define KNBR    32
#define EMB     128
#define FB      16      // f-rows per block (3125 * 16 == 50000 exactly)
#define RPW     4       // rows per wave (4 waves * 4 = 16)

// One fused kernel:
//  Phase A (per-wave, independent): gather 32 neighbor rows (float2/lane,
//    coalesced 512B per row), rank-1 attention score via butterfly reduce,
//    softmax over K=32, weighted aggregate; stage cat=[emb_f, agg] in LDS.
//  Phase B (block-wide): gate = sigmoid(cat @ W^T + b); out = g*embf+(1-g)*agg.
//    Mapping: thread t -> column pair (2p,2p+1), wave g -> j-quarter [64g,64g+64)
//    so W (128KB) is read exactly once per block (L2-resident across blocks).
__global__ __launch_bounds__(256, 4)
void fused_gnn(const int*   __restrict__ adj,    // [F,K] int32
               const float* __restrict__ embi,   // [N,E]
               const float* __restrict__ embf,   // [F,E]
               const float* __restrict__ u,      // [E,1]
               const float* __restrict__ W,      // [E,2E]
               const float* __restrict__ bias,   // [E]
               float*       __restrict__ out)    // [F,E]
{
    __shared__ float catbuf[FB][2 * EMB];  // 16 KB: [r][0:128)=embf, [128:256)=agg
    __shared__ float pbuf[FB][EMB];        //  8 KB: partial sums across waves

    const int tid   = threadIdx.x;
    const int wave  = tid >> 6;
    const int lane  = tid & 63;
    const int fbase = blockIdx.x * FB;

    // per-lane u values for columns 2*lane, 2*lane+1
    const float2 uv = *(const float2*)(u + 2 * lane);

    // ---------------- Phase A: attention, RPW rows per wave ----------------
    for (int i = 0; i < RPW; ++i) {
        const int r = wave * RPW + i;
        const int f = fbase + r;

        // lane holds index for k = lane&31 (upper half duplicates)
        const int myidx = adj[f * KNBR + (lane & 31)];

        // gather neighbor tile into registers: n[k] = embi[idx_k][2l..2l+1]
        float2 n[KNBR];
#pragma unroll
        for (int k = 0; k < KNBR; ++k) {
            const int ik = __shfl(myidx, k);
            n[k] = *(const float2*)(embi + (size_t)ik * EMB + 2 * lane);
        }

        // per-lane partial dot with u for every k
        float v[KNBR];
#pragma unroll
        for (int k = 0; k < KNBR; ++k)
            v[k] = n[k].x * uv.x + n[k].y * uv.y;

        // Butterfly multi-value reduction over lanes (bits 16,8,4,2,1).
        // Invariant: processing bits high->low leaves lane holding the full
        // 32-lane sum for k = lane&31. (bit step: lower keeps first half of
        // its current k-set, upper keeps second half; k = sum of kept bits.)
#pragma unroll
        for (int bit = 16; bit >= 1; bit >>= 1) {
            const bool upper = (lane & bit) != 0;
#pragma unroll
            for (int j = 0; j < bit; ++j) {   // half = bit
                const float send = upper ? v[j] : v[j + bit];
                const float recv = __shfl_xor(send, bit);
                v[j] = (upper ? v[j + bit] : v[j]) + recv;
            }
        }
        // fold the two 32-lane halves: lanes l and l+32 now both hold alpha[k=l&31]
        float alpha = v[0] + __shfl_xor(v[0], 32);

        // additive pad mask (index 0 = pad)
        alpha += (myidx != 0) ? 0.0f : -10000.0f;

        // softmax over the 32 k's (lanes 0..31 / 32..63 hold identical data)
        float mx = alpha;
#pragma unroll
        for (int bit = 1; bit <= 16; bit <<= 1)
            mx = fmaxf(mx, __shfl_xor(mx, bit));
        const float e = __expf(alpha - mx);
        float s = e;
#pragma unroll
        for (int bit = 1; bit <= 16; bit <<= 1)
            s += __shfl_xor(s, bit);
        const float an = e / s;   // normalized alpha for k = lane&31

        // aggregate: agg[c] = sum_k an[k] * n[k][c]
        float2 acc = make_float2(0.f, 0.f);
#pragma unroll
        for (int k = 0; k < KNBR; ++k) {
            const float a = __shfl(an, k);   // lane k holds an for k
            acc.x += a * n[k].x;
            acc.y += a * n[k].y;
        }

        // stage cat = [embf_row, agg] into LDS
        const float2 ef = *(const float2*)(embf + (size_t)f * EMB + 2 * lane);
        *(float2*)&catbuf[r][2 * lane]       = ef;
        *(float2*)&catbuf[r][EMB + 2 * lane] = acc;
    }
    __syncthreads();

    // ---------------- Phase B: gate GEMM + blend ----------------
    // thread -> (column pair c0=2p,c1=2p+1 ; j-quarter g = wave)
    const int p  = tid & 63;
    const int g  = tid >> 6;       // == wave (divergence is wave-uniform)
    const int c0 = 2 * p, c1 = c0 + 1;
    const int jbase = g * 64;

    float acc0[FB], acc1[FB];
#pragma unroll
    for (int r = 0; r < FB; ++r) { acc0[r] = 0.f; acc1[r] = 0.f; }

    const float* W0 = W + (size_t)c0 * (2 * EMB) + jbase;
    const float* W1 = W + (size_t)c1 * (2 * EMB) + jbase;

#pragma unroll 4
    for (int j = 0; j < 64; j += 4) {
        const float4 w0 = *(const float4*)(W0 + j);
        const float4 w1 = *(const float4*)(W1 + j);
#pragma unroll
        for (int r = 0; r < FB; ++r) {
            const float4 cv = *(const float4*)&catbuf[r][jbase + j];  // broadcast
            acc0[r] += cv.x * w0.x + cv.y * w0.y + cv.z * w0.z + cv.w * w0.w;
            acc1[r] += cv.x * w1.x + cv.y * w1.y + cv.z * w1.z + cv.w * w1.w;
        }
    }

    // combine the 4 j-quarter partials via LDS (wave-serialized, cheap)
    if (g == 3) {
#pragma unroll
        for (int r = 0; r < FB; ++r) { pbuf[r][c0] = acc0[r]; pbuf[r][c1] = acc1[r]; }
    }
    __syncthreads();
    if (g == 2) {
#pragma unroll
        for (int r = 0; r < FB; ++r) { pbuf[r][c0] += acc0[r]; pbuf[r][c1] += acc1[r]; }
    }
    __syncthreads();
    if (g == 1) {
#pragma unroll
        for (int r = 0; r < FB; ++r) { pbuf[r][c0] += acc0[r]; pbuf[r][c1] += acc1[r]; }
    }
    __syncthreads();
    if (g == 0) {
        const float2 bv = *(const float2*)(bias + c0);
#pragma unroll
        for (int r = 0; r < FB; ++r) {
            const float t0 = acc0[r] + pbuf[r][c0] + bv.x;
            const float t1 = acc1[r] + pbuf[r][c1] + bv.y;
            const float g0 = 1.f / (1.f + __expf(-t0));
            const float g1 = 1.f / (1.f + __expf(-t1));
            const float e0 = catbuf[r][c0],       e1 = catbuf[r][c1];
            const float a0 = catbuf[r][EMB + c0], a1 = catbuf[r][EMB + c1];
            float2 o;
            o.x = g0 * e0 + (1.f - g0) * a0;
            o.y = g1 * e1 + (1.f - g1) * a1;
            *(float2*)(out + (size_t)(fbase + r) * EMB + c0) = o;
        }
    }
}

extern "C" void kernel_launch(void* const* d_in, const int* in_sizes, int n_in,
                              void* d_out, int out_size, void* d_ws, size_t ws_size,
                              hipStream_t stream) {
    const int*   adj  = (const int*)  d_in[0];  // adjacency_fi [F,K] int32
    const float* embi = (const float*)d_in[1];  // embedding_i [N,E]
    const float* embf = (const float*)d_in[2];  // embedding_f_weight [F,E]
    const float* u    = (const float*)d_in[3];  // u [E,1]
    const float* W    = (const float*)d_in[4];  // W_weight [E,2E]
    const float* bias = (const float*)d_in[5];  // W_bias [E]
    float* outp = (float*)d_out;

    // 50000 = 3125 * 16 exactly -> no tail guard needed
    fused_gnn<<<F_TOTAL / FB, 256, 0, stream>>>(adj, embi, embf, u, W, bias, outp);
}

// Round 2
// 324.161 us; speedup vs baseline: 2.2073x; 2.2073x over previous
//
#include <hip/hip_runtime.h>

// Problem constants (from reference): F=50000, K=32, E=128, N=100000
#define F_TOTAL 50000
#define KNBR    32
#define EMB     128
#define FB      16      // f-rows per block (3125 * 16 == 50000 exactly)
#define RPW     4       // rows per wave (4 waves * 4 = 16)
#define CHK     8       // neighbor chunk size for online softmax

// Fused GNN layer.
// Phase A (per-wave): chunked ONLINE-softmax attention. Per chunk of 8
//   neighbors: gather 8 rows (float2/lane = 512B coalesced per row, only 16
//   VGPRs live -> no spill, unlike round-1's n[32] tile), partial dots with u,
//   multi-value butterfly reduce (bits 4,2,1 then xor 8/16/32) so lane holds
//   alpha for k = chunk*8 + (lane&7), then flash-style update of running
//   (m, s, acc) re-using the 8 rows still in registers.
// Phase B (block-wide): gate = sigmoid(cat @ W^T + b); out = g*embf+(1-g)*agg.
//   thread -> column pair, wave -> j-quarter; W (128KB) read once per block.
__global__ __launch_bounds__(256, 4)
void fused_gnn(const int*   __restrict__ adj,    // [F,K] int32
               const float* __restrict__ embi,   // [N,E]
               const float* __restrict__ embf,   // [F,E]
               const float* __restrict__ u,      // [E,1]
               const float* __restrict__ W,      // [E,2E]
               const float* __restrict__ bias,   // [E]
               float*       __restrict__ out)    // [F,E]
{
    __shared__ float catbuf[FB][2 * EMB];  // 16 KB: [r][0:128)=embf, [128:256)=agg
    __shared__ float pbuf[FB][EMB];        //  8 KB: Phase-B partial sums

    const int tid   = threadIdx.x;
    const int wave  = tid >> 6;
    const int lane  = tid & 63;
    const int fbase = blockIdx.x * FB;

    // per-lane u values for columns 2*lane, 2*lane+1
    const float2 uv = *(const float2*)(u + 2 * lane);

    // ---------------- Phase A: online-softmax attention ----------------
    for (int i = 0; i < RPW; ++i) {
        const int r = wave * RPW + i;
        const int f = fbase + r;

        // lane holds index for k = lane&31 (upper half duplicates)
        const int myidx = adj[f * KNBR + (lane & 31)];

        float m = -3.0e38f;                 // running max
        float s = 0.0f;                     // running denom
        float2 acc = make_float2(0.f, 0.f); // running weighted sum (cols 2l,2l+1)

#pragma unroll
        for (int c = 0; c < KNBR / CHK; ++c) {
            // gather 8 neighbor rows; one fully-coalesced 512B request each
            float2 nb[CHK];
#pragma unroll
            for (int j = 0; j < CHK; ++j) {
                const int ik = __shfl(myidx, c * CHK + j);
                nb[j] = *(const float2*)(embi + (size_t)ik * EMB + 2 * lane);
            }

            // per-lane partial dots with u
            float v[CHK];
#pragma unroll
            for (int j = 0; j < CHK; ++j)
                v[j] = nb[j].x * uv.x + nb[j].y * uv.y;

            // multi-value butterfly over bits 4,2,1: lane ends holding the
            // 8-lane-group partial for k_local = lane&7 (verified mapping,
            // same construction as the 32-value version that passed round 1)
#pragma unroll
            for (int bit = 4; bit >= 1; bit >>= 1) {
                const bool upper = (lane & bit) != 0;
#pragma unroll
                for (int j = 0; j < bit; ++j) {
                    const float send = upper ? v[j] : v[j + bit];
                    const float recv = __shfl_xor(send, bit);
                    v[j] = (upper ? v[j + bit] : v[j]) + recv;
                }
            }
            // finish sum across remaining lane bits 8,16,32
            float alpha = v[0];
            alpha += __shfl_xor(alpha, 8);
            alpha += __shfl_xor(alpha, 16);
            alpha += __shfl_xor(alpha, 32);
            // alpha is now the full dot for k = c*8 + (lane&7), replicated
            // across the 8 lane-groups.

            // additive pad mask (index 0 = pad) for this lane's k
            const int ikown = __shfl(myidx, c * CHK + (lane & 7));
            alpha += (ikown != 0) ? 0.0f : -10000.0f;

            // chunk max over the 8 k's (lanes differing in bits 1,2,4)
            float cm = alpha;
            cm = fmaxf(cm, __shfl_xor(cm, 1));
            cm = fmaxf(cm, __shfl_xor(cm, 2));
            cm = fmaxf(cm, __shfl_xor(cm, 4));

            // online rescale
            const float mnew  = fmaxf(m, cm);
            const float scale = __expf(m - mnew);   // 0 on first chunk
            s *= scale;
            acc.x *= scale;
            acc.y *= scale;
            m = mnew;

            // exp weights; denom contribution
            const float e = __expf(alpha - mnew);   // own k's weight
            float se = e;
            se += __shfl_xor(se, 1);
            se += __shfl_xor(se, 2);
            se += __shfl_xor(se, 4);
            s += se;

            // weighted accumulate, re-using the register-resident rows:
            // lane j holds e for k_local = j
#pragma unroll
            for (int j = 0; j < CHK; ++j) {
                const float w = __shfl(e, j);
                acc.x += w * nb[j].x;
                acc.y += w * nb[j].y;
            }
        }

        const float inv = 1.0f / s;
        acc.x *= inv;
        acc.y *= inv;

        // stage cat = [embf_row, agg] into LDS
        const float2 ef = *(const float2*)(embf + (size_t)f * EMB + 2 * lane);
        *(float2*)&catbuf[r][2 * lane]       = ef;
        *(float2*)&catbuf[r][EMB + 2 * lane] = acc;
    }
    __syncthreads();

    // ---------------- Phase B: gate GEMM + blend ----------------
    // thread -> (column pair c0=2p,c1=2p+1 ; j-quarter g = wave)
    const int p  = tid & 63;
    const int g  = tid >> 6;       // == wave (divergence is wave-uniform)
    const int c0 = 2 * p, c1 = c0 + 1;
    const int jbase = g * 64;

    float acc0[FB], acc1[FB];
#pragma unroll
    for (int r = 0; r < FB; ++r) { acc0[r] = 0.f; acc1[r] = 0.f; }

    const float* W0 = W + (size_t)c0 * (2 * EMB) + jbase;
    const float* W1 = W + (size_t)c1 * (2 * EMB) + jbase;

#pragma unroll 4
    for (int j = 0; j < 64; j += 4) {
        const float4 w0 = *(const float4*)(W0 + j);
        const float4 w1 = *(const float4*)(W1 + j);
#pragma unroll
        for (int r = 0; r < FB; ++r) {
            const float4 cv = *(const float4*)&catbuf[r][jbase + j];  // broadcast
            acc0[r] += cv.x * w0.x + cv.y * w0.y + cv.z * w0.z + cv.w * w0.w;
            acc1[r] += cv.x * w1.x + cv.y * w1.y + cv.z * w1.z + cv.w * w1.w;
        }
    }

    // combine the 4 j-quarter partials via LDS (wave-serialized, cheap)
    if (g == 3) {
#pragma unroll
        for (int r = 0; r < FB; ++r) { pbuf[r][c0] = acc0[r]; pbuf[r][c1] = acc1[r]; }
    }
    __syncthreads();
    if (g == 2) {
#pragma unroll
        for (int r = 0; r < FB; ++r) { pbuf[r][c0] += acc0[r]; pbuf[r][c1] += acc1[r]; }
    }
    __syncthreads();
    if (g == 1) {
#pragma unroll
        for (int r = 0; r < FB; ++r) { pbuf[r][c0] += acc0[r]; pbuf[r][c1] += acc1[r]; }
    }
    __syncthreads();
    if (g == 0) {
        const float2 bv = *(const float2*)(bias + c0);
#pragma unroll
        for (int r = 0; r < FB; ++r) {
            const float t0 = acc0[r] + pbuf[r][c0] + bv.x;
            const float t1 = acc1[r] + pbuf[r][c1] + bv.y;
            const float g0 = 1.f / (1.f + __expf(-t0));
            const float g1 = 1.f / (1.f + __expf(-t1));
            const float e0 = catbuf[r][c0],       e1 = catbuf[r][c1];
            const float a0 = catbuf[r][EMB + c0], a1 = catbuf[r][EMB + c1];
            float2 o;
            o.x = g0 * e0 + (1.f - g0) * a0;
            o.y = g1 * e1 + (1.f - g1) * a1;
            *(float2*)(out + (size_t)(fbase + r) * EMB + c0) = o;
        }
    }
}

extern "C" void kernel_launch(void* const* d_in, const int* in_sizes, int n_in,
                              void* d_out, int out_size, void* d_ws, size_t ws_size,
                              hipStream_t stream) {
    const int*   adj  = (const int*)  d_in[0];  // adjacency_fi [F,K] int32
    const float* embi = (const float*)d_in[1];  // embedding_i [N,E]
    const float* embf = (const float*)d_in[2];  // embedding_f_weight [F,E]
    const float* u    = (const float*)d_in[3];  // u [E,1]
    const float* W    = (const float*)d_in[4];  // W_weight [E,2E]
    const float* bias = (const float*)d_in[5];  // W_bias [E]
    float* outp = (float*)d_out;

    // 50000 = 3125 * 16 exactly -> no tail guard needed
    fused_gnn<<<F_TOTAL / FB, 256, 0, stream>>>(adj, embi, embf, u, W, bias, outp);
}

// Round 3
// 265.002 us; speedup vs baseline: 2.7000x; 1.2232x over previous
//
#include <hip/hip_runtime.h>

// Problem constants (from reference): F=50000, K=32, E=128, N=100000
#define F_TOTAL 50000
#define N_NODE  100000
#define KNBR    32
#define EMB     128
#define FB      16      // f-rows per block (3125 * 16 == 50000 exactly)
#define RPW     4       // rows per wave (4 waves * 4 = 16)

// ---------------------------------------------------------------------------
// Kernel 1: y[n] = embi[n] . u   (rank-1 attention score is f-independent!)
// Wave-per-row, float2/lane coalesced 512B reads, 6-step butterfly reduce.
// 100000 rows = 3125 blocks * 4 waves * 8 iters exactly.
// ---------------------------------------------------------------------------
__global__ __launch_bounds__(256)
void node_scores(const float* __restrict__ embi,
                 const float* __restrict__ u,
                 float*       __restrict__ y)
{
    const int wave = threadIdx.x >> 6;
    const int lane = threadIdx.x & 63;
    const float2 uv = *(const float2*)(u + 2 * lane);

    const int stride = gridDim.x * 4;
    for (int row = blockIdx.x * 4 + wave; row < N_NODE; row += stride) {
        const float2 v = *(const float2*)(embi + (size_t)row * EMB + 2 * lane);
        float d = v.x * uv.x + v.y * uv.y;
#pragma unroll
        for (int bit = 1; bit <= 32; bit <<= 1)
            d += __shfl_xor(d, bit);
        if (lane == 0) y[row] = d;
    }
}

// ---------------------------------------------------------------------------
// Kernel 2: fused attention + gated fusion.
// Phase A (per wave, per row): alpha = y[adj[f,k]] + mask (4B gather from the
//   L2-resident 400KB y table), full 32-wide softmax upfront (10 shfl), then
//   aggregate: per k, readlane(idx)/readlane(an) -> SGPR (SALU address math,
//   FMA with SGPR operand), 32 independent coalesced 512B row loads.
// Phase B (block-wide): gate = sigmoid(cat @ W^T + b); out = g*embf+(1-g)*agg.
// ---------------------------------------------------------------------------
__global__ __launch_bounds__(256, 4)
void fused_gnn(const int*   __restrict__ adj,    // [F,K] int32
               const float* __restrict__ embi,   // [N,E]
               const float* __restrict__ embf,   // [F,E]
               const float* __restrict__ y,      // [N] precomputed scores
               const float* __restrict__ W,      // [E,2E]
               const float* __restrict__ bias,   // [E]
               float*       __restrict__ out)    // [F,E]
{
    __shared__ float catbuf[FB][2 * EMB];  // 16 KB: [r][0:128)=embf, [128:256)=agg
    __shared__ float pbuf[FB][EMB];        //  8 KB: Phase-B partial sums

    const int tid   = threadIdx.x;
    const int wave  = tid >> 6;
    const int lane  = tid & 63;
    const int fbase = blockIdx.x * FB;

    // ---------------- Phase A: attention ----------------
    for (int i = 0; i < RPW; ++i) {
        const int r = wave * RPW + i;
        const int f = fbase + r;

        // lane holds neighbor k = lane&31 (upper 32 lanes duplicate)
        const int myidx = adj[f * KNBR + (lane & 31)];

        // score gather + pad mask (index 0 = pad)
        float alpha = y[myidx] + ((myidx != 0) ? 0.0f : -10000.0f);

        // softmax over the 32 k's (bits 1..16 keep the two half-waves
        // independent; they hold identical data)
        float mx = alpha;
#pragma unroll
        for (int bit = 1; bit <= 16; bit <<= 1)
            mx = fmaxf(mx, __shfl_xor(mx, bit));
        const float e = __expf(alpha - mx);
        float s = e;
#pragma unroll
        for (int bit = 1; bit <= 16; bit <<= 1)
            s += __shfl_xor(s, bit);
        const float an = e / s;   // normalized weight for k = lane&31

        // aggregate: agg[c] = sum_k an[k] * embi[idx_k][c]
        // readlane -> wave-uniform SGPR index/weight: SALU address math,
        // 32 independent 512B coalesced loads, FMA with SGPR operand.
        float2 acc = make_float2(0.f, 0.f);
#pragma unroll
        for (int k = 0; k < KNBR; ++k) {
            const int   iks = __builtin_amdgcn_readlane(myidx, k);
            const float a   = __uint_as_float(
                (unsigned)__builtin_amdgcn_readlane((int)__float_as_uint(an), k));
            const float* rowp = embi + (size_t)(unsigned)iks * EMB;
            const float2 nb = *(const float2*)(rowp + 2 * lane);
            acc.x = fmaf(a, nb.x, acc.x);
            acc.y = fmaf(a, nb.y, acc.y);
        }

        // stage cat = [embf_row, agg] into LDS
        const float2 ef = *(const float2*)(embf + (size_t)f * EMB + 2 * lane);
        *(float2*)&catbuf[r][2 * lane]       = ef;
        *(float2*)&catbuf[r][EMB + 2 * lane] = acc;
    }
    __syncthreads();

    // ---------------- Phase B: gate GEMM + blend ----------------
    // thread -> (column pair c0=2p,c1=2p+1 ; j-quarter g = wave)
    const int p  = tid & 63;
    const int g  = tid >> 6;       // == wave (divergence is wave-uniform)
    const int c0 = 2 * p, c1 = c0 + 1;
    const int jbase = g * 64;

    float acc0[FB], acc1[FB];
#pragma unroll
    for (int r = 0; r < FB; ++r) { acc0[r] = 0.f; acc1[r] = 0.f; }

    const float* W0 = W + (size_t)c0 * (2 * EMB) + jbase;
    const float* W1 = W + (size_t)c1 * (2 * EMB) + jbase;

#pragma unroll 4
    for (int j = 0; j < 64; j += 4) {
        const float4 w0 = *(const float4*)(W0 + j);
        const float4 w1 = *(const float4*)(W1 + j);
#pragma unroll
        for (int r = 0; r < FB; ++r) {
            const float4 cv = *(const float4*)&catbuf[r][jbase + j];  // broadcast
            acc0[r] += cv.x * w0.x + cv.y * w0.y + cv.z * w0.z + cv.w * w0.w;
            acc1[r] += cv.x * w1.x + cv.y * w1.y + cv.z * w1.z + cv.w * w1.w;
        }
    }

    // combine the 4 j-quarter partials via LDS (wave-serialized, cheap)
    if (g == 3) {
#pragma unroll
        for (int r = 0; r < FB; ++r) { pbuf[r][c0] = acc0[r]; pbuf[r][c1] = acc1[r]; }
    }
    __syncthreads();
    if (g == 2) {
#pragma unroll
        for (int r = 0; r < FB; ++r) { pbuf[r][c0] += acc0[r]; pbuf[r][c1] += acc1[r]; }
    }
    __syncthreads();
    if (g == 1) {
#pragma unroll
        for (int r = 0; r < FB; ++r) { pbuf[r][c0] += acc0[r]; pbuf[r][c1] += acc1[r]; }
    }
    __syncthreads();
    if (g == 0) {
        const float2 bv = *(const float2*)(bias + c0);
#pragma unroll
        for (int r = 0; r < FB; ++r) {
            const float t0 = acc0[r] + pbuf[r][c0] + bv.x;
            const float t1 = acc1[r] + pbuf[r][c1] + bv.y;
            const float g0 = 1.f / (1.f + __expf(-t0));
            const float g1 = 1.f / (1.f + __expf(-t1));
            const float e0 = catbuf[r][c0],       e1 = catbuf[r][c1];
            const float a0 = catbuf[r][EMB + c0], a1 = catbuf[r][EMB + c1];
            float2 o;
            o.x = g0 * e0 + (1.f - g0) * a0;
            o.y = g1 * e1 + (1.f - g1) * a1;
            *(float2*)(out + (size_t)(fbase + r) * EMB + c0) = o;
        }
    }
}

extern "C" void kernel_launch(void* const* d_in, const int* in_sizes, int n_in,
                              void* d_out, int out_size, void* d_ws, size_t ws_size,
                              hipStream_t stream) {
    const int*   adj  = (const int*)  d_in[0];  // adjacency_fi [F,K] int32
    const float* embi = (const float*)d_in[1];  // embedding_i [N,E]
    const float* embf = (const float*)d_in[2];  // embedding_f_weight [F,E]
    const float* u    = (const float*)d_in[3];  // u [E,1]
    const float* W    = (const float*)d_in[4];  // W_weight [E,2E]
    const float* bias = (const float*)d_in[5];  // W_bias [E]
    float* outp = (float*)d_out;
    float* y    = (float*)d_ws;                 // N_NODE floats (400 KB scratch)

    node_scores<<<3125, 256, 0, stream>>>(embi, u, y);
    fused_gnn<<<F_TOTAL / FB, 256, 0, stream>>>(adj, embi, embf, y, W, bias, outp);
}

// Round 5
// 261.061 us; speedup vs baseline: 2.7408x; 1.0151x over previous
//
#include <hip/hip_runtime.h>

// Problem constants (from reference): F=50000, K=32, E=128, N=100000
#define F_TOTAL 50000
#define N_NODE  100000
#define KNBR    32
#define EMB     128
#define FB      16      // f-rows per block (3125 * 16 == 50000 exactly)
#define RPW     4       // rows per wave (4 waves * 4 = 16)

// ---------------------------------------------------------------------------
// Kernel 1: y[n] = embi[n] . u
// 8 rows per wave per iteration: 8 independent 512B loads, 8 dots, then a
// multi-value butterfly (bits 4,2,1 -> lane holds 8-lane-group partial for
// row j = lane&7) + xor 8/16/32 folds. 10 shfl per 8 rows (vs 48 before).
// 3125 blocks * 4 waves * 8 rows = 100000 exactly -> single iteration.
// ---------------------------------------------------------------------------
__global__ __launch_bounds__(256)
void node_scores(const float* __restrict__ embi,
                 const float* __restrict__ u,
                 float*       __restrict__ y)
{
    const int wave = threadIdx.x >> 6;
    const int lane = threadIdx.x & 63;
    const float2 uv = *(const float2*)(u + 2 * lane);

    const int base = (blockIdx.x * 4 + wave) * 8;

    float v[8];
#pragma unroll
    for (int j = 0; j < 8; ++j) {
        const float2 e = *(const float2*)(embi + (size_t)(base + j) * EMB + 2 * lane);
        v[j] = e.x * uv.x + e.y * uv.y;
    }

    // butterfly over bits 4,2,1: lane ends holding, for row j = lane&7,
    // the sum over its 8-lane group (same construction as verified round 1)
#pragma unroll
    for (int bit = 4; bit >= 1; bit >>= 1) {
        const bool upper = (lane & bit) != 0;
#pragma unroll
        for (int j = 0; j < bit; ++j) {
            const float send = upper ? v[j] : v[j + bit];
            const float recv = __shfl_xor(send, bit);
            v[j] = (upper ? v[j + bit] : v[j]) + recv;
        }
    }
    float d = v[0];
    d += __shfl_xor(d, 8);
    d += __shfl_xor(d, 16);
    d += __shfl_xor(d, 32);   // full 64-lane sum for row base + (lane&7)

    if (lane < 8) y[base + lane] = d;
}

// ---------------------------------------------------------------------------
// Kernel 2: fused attention + gated fusion.
// Phase A: alpha = y[adj[f,k]] + mask, 32-wide softmax (10 shfl), then the
//   aggregate with DOUBLE-BUFFERED register batches of 8 rows -> up to 16
//   outstanding 512B loads per wave (round 3 had ~8, VGPR-starved at 52).
// Phase B: gate = sigmoid(cat @ W^T + b); out = g*embf + (1-g)*agg.
//   thread -> column pair, wave -> j-quarter; W (128KB) read once per block.
// ---------------------------------------------------------------------------
__global__ __launch_bounds__(256, 4)
void fused_gnn(const int*   __restrict__ adj,    // [F,K] int32
               const float* __restrict__ embi,   // [N,E]
               const float* __restrict__ embf,   // [F,E]
               const float* __restrict__ y,      // [N] precomputed scores
               const float* __restrict__ W,      // [E,2E]
               const float* __restrict__ bias,   // [E]
               float*       __restrict__ out)    // [F,E]
{
    __shared__ float catbuf[FB][2 * EMB];  // 16 KB
    __shared__ float pbuf[FB][EMB];        //  8 KB

    const int tid   = threadIdx.x;
    const int wave  = tid >> 6;
    const int lane  = tid & 63;
    const int fbase = blockIdx.x * FB;

    // ---------------- Phase A: attention ----------------
    for (int i = 0; i < RPW; ++i) {
        const int r = wave * RPW + i;
        const int f = fbase + r;

        const int myidx = adj[f * KNBR + (lane & 31)];

        // score gather + pad mask (index 0 = pad)
        float alpha = y[myidx] + ((myidx != 0) ? 0.0f : -10000.0f);

        // softmax over the 32 k's (half-waves hold identical data)
        float mx = alpha;
#pragma unroll
        for (int bit = 1; bit <= 16; bit <<= 1)
            mx = fmaxf(mx, __shfl_xor(mx, bit));
        const float e = __expf(alpha - mx);
        float s = e;
#pragma unroll
        for (int bit = 1; bit <= 16; bit <<= 1)
            s += __shfl_xor(s, bit);
        const float an = e / s;   // normalized weight for k = lane&31

        // embf row load issued early, consumed at the end
        const float2 ef = *(const float2*)(embf + (size_t)f * EMB + 2 * lane);

        // aggregate with double-buffered batches of 8 (16 loads in flight)
        float2 nbA[8], nbB[8];
#pragma unroll
        for (int j = 0; j < 8; ++j) {
            const unsigned ik = (unsigned)__builtin_amdgcn_readlane(myidx, j);
            nbA[j] = *(const float2*)(embi + (size_t)ik * EMB + 2 * lane);
        }

        float2 acc = make_float2(0.f, 0.f);
#pragma unroll
        for (int g = 0; g < 4; ++g) {
            float2* cur = (g & 1) ? nbB : nbA;   // folds to static after unroll
            float2* nxt = (g & 1) ? nbA : nbB;
            if (g < 3) {
#pragma unroll
                for (int j = 0; j < 8; ++j) {
                    const unsigned ik =
                        (unsigned)__builtin_amdgcn_readlane(myidx, (g + 1) * 8 + j);
                    nxt[j] = *(const float2*)(embi + (size_t)ik * EMB + 2 * lane);
                }
            }
#pragma unroll
            for (int j = 0; j < 8; ++j) {
                const float a = __uint_as_float((unsigned)__builtin_amdgcn_readlane(
                    (int)__float_as_uint(an), g * 8 + j));
                acc.x = fmaf(a, cur[j].x, acc.x);
                acc.y = fmaf(a, cur[j].y, acc.y);
            }
        }

        // stage cat = [embf_row, agg] into LDS
        *(float2*)&catbuf[r][2 * lane]       = ef;
        *(float2*)&catbuf[r][EMB + 2 * lane] = acc;
    }
    __syncthreads();

    // ---------------- Phase B: gate GEMM + blend ----------------
    const int p  = tid & 63;
    const int g  = tid >> 6;       // == wave (divergence is wave-uniform)
    const int c0 = 2 * p, c1 = c0 + 1;
    const int jbase = g * 64;

    float acc0[FB], acc1[FB];
#pragma unroll
    for (int r = 0; r < FB; ++r) { acc0[r] = 0.f; acc1[r] = 0.f; }

    const float* W0 = W + (size_t)c0 * (2 * EMB) + jbase;
    const float* W1 = W + (size_t)c1 * (2 * EMB) + jbase;

#pragma unroll 4
    for (int j = 0; j < 64; j += 4) {
        const float4 w0 = *(const float4*)(W0 + j);
        const float4 w1 = *(const float4*)(W1 + j);
#pragma unroll
        for (int r = 0; r < FB; ++r) {
            const float4 cv = *(const float4*)&catbuf[r][jbase + j];  // broadcast
            acc0[r] += cv.x * w0.x + cv.y * w0.y + cv.z * w0.z + cv.w * w0.w;
            acc1[r] += cv.x * w1.x + cv.y * w1.y + cv.z * w1.z + cv.w * w1.w;
        }
    }

    // combine the 4 j-quarter partials via LDS (wave-serialized, cheap)
    if (g == 3) {
#pragma unroll
        for (int r = 0; r < FB; ++r) { pbuf[r][c0] = acc0[r]; pbuf[r][c1] = acc1[r]; }
    }
    __syncthreads();
    if (g == 2) {
#pragma unroll
        for (int r = 0; r < FB; ++r) { pbuf[r][c0] += acc0[r]; pbuf[r][c1] += acc1[r]; }
    }
    __syncthreads();
    if (g == 1) {
#pragma unroll
        for (int r = 0; r < FB; ++r) { pbuf[r][c0] += acc0[r]; pbuf[r][c1] += acc1[r]; }
    }
    __syncthreads();
    if (g == 0) {
        const float2 bv = *(const float2*)(bias + c0);
#pragma unroll
        for (int r = 0; r < FB; ++r) {
            const float t0 = acc0[r] + pbuf[r][c0] + bv.x;
            const float t1 = acc1[r] + pbuf[r][c1] + bv.y;
            const float g0 = 1.f / (1.f + __expf(-t0));
            const float g1 = 1.f / (1.f + __expf(-t1));
            const float e0 = catbuf[r][c0],       e1 = catbuf[r][c1];
            const float a0 = catbuf[r][EMB + c0], a1 = catbuf[r][EMB + c1];
            float2 o;
            o.x = g0 * e0 + (1.f - g0) * a0;
            o.y = g1 * e1 + (1.f - g1) * a1;
            *(float2*)(out + (size_t)(fbase + r) * EMB + c0) = o;
        }
    }
}

extern "C" void kernel_launch(void* const* d_in, const int* in_sizes, int n_in,
                              void* d_out, int out_size, void* d_ws, size_t ws_size,
                              hipStream_t stream) {
    const int*   adj  = (const int*)  d_in[0];  // adjacency_fi [F,K] int32
    const float* embi = (const float*)d_in[1];  // embedding_i [N,E]
    const float* embf = (const float*)d_in[2];  // embedding_f_weight [F,E]
    const float* u    = (const float*)d_in[3];  // u [E,1]
    const float* W    = (const float*)d_in[4];  // W_weight [E,2E]
    const float* bias = (const float*)d_in[5];  // W_bias [E]
    float* outp = (float*)d_out;
    float* y    = (float*)d_ws;                 // N_NODE floats (400 KB scratch)

    node_scores<<<3125, 256, 0, stream>>>(embi, u, y);
    fused_gnn<<<F_TOTAL / FB, 256, 0, stream>>>(adj, embi, embf, y, W, bias, outp);
}